// Round 2
// baseline (58.010 us; speedup 1.0000x reference)
//
#include <hip/hip_runtime.h>

// Double-pendulum Hamiltonian dynamics, closed form, fp32 in/out.
// Input y: (B,4) f32 = (th1, th2, p1, p2). Output: (B,4) f32 =
// (dth1, dth2, dp1, dp2) where (M1=M2=L1=L2=1, G=9.81):
//   c = cos(th1-th2), s = sin(th1-th2), det = 2 - c^2
//   dth1 = (p1 - c*p2)/det
//   dth2 = (2*p2 - c*p1)/det
//   dp1  = -s*dth1*dth2 - 2*G*sin(th1)
//   dp2  =  s*dth1*dth2 -   G*sin(th2)
// Derivation: T = 0.5*p^T M^-1 p with M=[[2,c],[c,1]], dT/dc = -dth1*dth2,
// dc/dth1 = -s, dc/dth2 = +s; V = G(3 - 2cos th1 - cos th2).

#define GCONST 9.81f

__global__ __launch_bounds__(256) void pendulum2dof_kernel(
    const float4* __restrict__ y, float4* __restrict__ out, int n) {
    int i = blockIdx.x * blockDim.x + threadIdx.x;
    if (i >= n) return;

    float4 v = y[i];
    float th1 = v.x;
    float th2 = v.y;
    float p1  = v.z;
    float p2  = v.w;

    float d = th1 - th2;
    float s, c;
    __sincosf(d, &s, &c);          // fast sincos; abs err ~1e-6, threshold is 0.63

    float det = 2.0f - c * c;      // det in [1,2], never singular
    float inv_det = __frcp_rn(det);

    float dth1 = (p1 - c * p2) * inv_det;
    float dth2 = (2.0f * p2 - c * p1) * inv_det;

    float cross = s * dth1 * dth2;
    float dp1 = -cross - 2.0f * GCONST * __sinf(th1);
    float dp2 =  cross -        GCONST * __sinf(th2);

    out[i] = make_float4(dth1, dth2, dp1, dp2);
}

extern "C" void kernel_launch(void* const* d_in, const int* in_sizes, int n_in,
                              void* d_out, int out_size, void* d_ws, size_t ws_size,
                              hipStream_t stream) {
    // d_in[0] = t (1 elem, unused ODE time); d_in[1] = y (B*4 float32)
    const float4* y = (const float4*)d_in[1];
    float4* out = (float4*)d_out;
    int n = in_sizes[1] / 4;  // number of states (B)
    int block = 256;
    int grid = (n + block - 1) / block;
    pendulum2dof_kernel<<<grid, block, 0, stream>>>(y, out, n);
}